// Round 10
// baseline (102.230 us; speedup 1.0000x reference)
//
#include <hip/hip_runtime.h>
#include <math.h>

// Problem constants (B=2, T=512, D=512)
#define NT   1024   // B*T tokens
#define TT   512    // T
#define DD   512    // D

// Extended Golay (24,12) generator, hardcoded (matches reference _golay()):
//   l <  12 : G[k][l] = (k==l)
//   l 12-22 : G[k][l] = (k+l)&1
//   l == 23 : G[k][l] = k&1
//
// PASSING STRATEGY (round 4, absmax 1.56e-2, stable r4-r9): faithful f32
// emulation of the f32 numpy reference — exact IEEE f32 ops (__f*_rn, no FMA
// contraction), correctly-rounded f32 sin/cos via f64 sincos, np.round =
// rintf, numpy's pairwise-summation order for norms, sequential-k fmaf GEMVs.
// DO NOT change any summation order that feeds round()/threshold decisions.
//
// ROUND 10 (perf; per-token arithmetic bit-identical to r9):
//  SINGLE fused kernel. The grid (256 blocks, 1/CU by capacity, <=2/CU by
//  resources) is fully co-resident, so a device-scope arrival-counter barrier
//  (agent-scope release fetch_add + relaxed spin + acquire load, per G16)
//  replaces the separate scale_kernel: f0/f1 stay in registers across the
//  barrier, each block redundantly reduces the 1024 f64 partials (smooth,
//  order-insensitive) and stores out once, scaled. Saves one dispatch + gap
//  and a 2MB out round-trip. Counter init: d_ws is poisoned to 0xAA before
//  every launch -> spin target 0xAAAAAAAA+256 (fallback 256 for zero-init;
//  sleep-loop cap ~5ms as anti-hang escape — all blocks arrive in ~10us).

// numpy pairwise sum of 512 floats, exact numpy order (see r4). Runs on
// lanes 0..31 of the calling token's wave 0 (htid = thread-in-token).
// Result valid at htid == 0.
__device__ __forceinline__ float np_pairwise512(const float* x, int htid) {
    float r = 0.0f;
    if (htid < 32) {
        const int b = htid >> 3, j = htid & 7;
        const float* p = x + 128 * b + j;
        r = p[0];
        #pragma unroll
        for (int i = 1; i < 16; i++) r = __fadd_rn(r, p[8 * i]);
    }
    r = __fadd_rn(r, __shfl_down(r, 1, 64));
    r = __fadd_rn(r, __shfl_down(r, 2, 64));
    r = __fadd_rn(r, __shfl_down(r, 4, 64));
    r = __fadd_rn(r, __shfl_down(r, 8, 64));
    r = __fadd_rn(r, __shfl_down(r, 16, 64));
    return r;
}

// numpy pairwise sum, n=12 (8<=n<=128 path): combine first 8, then
// sequential remainder a[8..11].
__device__ __forceinline__ float np_pairwise12(const float* a) {
    float r = __fadd_rn(__fadd_rn(__fadd_rn(a[0], a[1]), __fadd_rn(a[2], a[3])),
                        __fadd_rn(__fadd_rn(a[4], a[5]), __fadd_rn(a[6], a[7])));
    r = __fadd_rn(r, a[8]);
    r = __fadd_rn(r, a[9]);
    r = __fadd_rn(r, a[10]);
    r = __fadd_rn(r, a[11]);
    return r;
}

__global__ __launch_bounds__(1024, 4) void token_kernel(
    const int*   __restrict__ token_ids,
    const float* __restrict__ resonances,
    const float* __restrict__ emb_scales,
    const float* __restrict__ emb_shifts,
    const float* __restrict__ emb_norm,
    const float* __restrict__ W_enc,   // [D,24] row-major
    const float* __restrict__ b_enc,   // [24]
    const float* __restrict__ W_dec,   // [24,D] row-major
    const float* __restrict__ b_dec,   // [D]
    const float* __restrict__ ecc_p,   // [1]
    const float* __restrict__ ep_p,    // [1]
    const float* __restrict__ frac_norm,
    float*       __restrict__ out,     // [NT*D] f32, written once (scaled)
    double*      __restrict__ partials,// [NT] per-token sum of squares
    unsigned*    __restrict__ counter) // arrival counter (poisoned 0xAAAAAAAA)
{
    const int tid  = threadIdx.x;
    const int q    = tid >> 8;        // token slot 0..3 (waves 4q..4q+3)
    const int htid = tid & 255;       // thread-in-token
    const int tok  = blockIdx.x * 4 + q;
    const int t    = tok % TT;
    const int w4   = htid >> 6;       // wave-in-token 0..3
    const int hlane = htid & 63;      // lane within wave (256-aligned split)

    __shared__ float  sh_w[DD * 24];   // staged W_enc (48 KB, shared by 4 tokens)
    __shared__ float  sh_e[4][DD];     // normalized emb
    __shared__ float  sh_x[4][DD];     // squares scratch
    __shared__ float  sh_c[4][24];     // corrected (decode output)
    __shared__ float  sh_sc[4][4];     // [q][0]: tok_norm, [2]: e_in2, [3]: e_out2
    __shared__ double sh_red[4][4];
    __shared__ double sh_fr[4];        // factor reduction
    __shared__ float  sh_factor;

    // ---- stage W_enc -> LDS (coalesced float4; hides under sincos; first
    //      consumer is after B3) ----
    {
        const float4* src = (const float4*)W_enc;
        float4*       dst = (float4*)sh_w;
        #pragma unroll
        for (int i = 0; i < 3; i++)           // 3 * 1024 = 3072 float4 = 48 KB
            dst[tid + 1024 * i] = src[tid + 1024 * i];
    }

    const float ecc   = ecc_p[0];
    const float ep    = ep_p[0];
    const float enorm = emb_norm[0];

    const int   idv  = token_ids[tok];                       // in [0,1e6): % identity
    const float tv   = __fdiv_rn((float)idv, 1000000.0f);    // exact np f32 div
    const float base = __fadd_rn(tv, (float)t);

    // ---- embedding (f32-exact): d0 = htid, d1 = htid+256 ----
    const int d0 = htid, d1 = htid + 256;
    float e0, e1;
    {
        const float a0 = __fmul_rn(resonances[d0], base);
        const float a1 = __fmul_rn(resonances[d1], base);
        // correctly-rounded f32 sin/cos via f64 sincos
        double s0d, c0d, s1d, c1d;
        sincos((double)a0, &s0d, &c0d);
        sincos((double)a1, &s1d, &c1d);
        const float s0 = (float)s0d, c0 = (float)c0d;
        const float s1 = (float)s1d, c1 = (float)c1d;
        const float comp0 = __fadd_rn(__fmul_rn(c0, __fadd_rn(1.0f, s0)), __fmul_rn(s0, s0));
        const float comp1 = __fadd_rn(__fmul_rn(c1, __fadd_rn(1.0f, s1)), __fmul_rn(s1, s1));
        e0 = __fadd_rn(__fmul_rn(comp0, emb_scales[d0]), emb_shifts[d0]);
        e1 = __fadd_rn(__fmul_rn(comp1, emb_scales[d1]), emb_shifts[d1]);
    }
    sh_x[q][d0] = __fmul_rn(e0, e0);
    sh_x[q][d1] = __fmul_rn(e1, e1);
    __syncthreads();                                         // B1

    // tok_norm (numpy pairwise + correctly-rounded sqrt)
    float ps = np_pairwise512(sh_x[q], htid);
    if (htid == 0) sh_sc[q][0] = __fsqrt_rn(ps);
    __syncthreads();                                         // B2
    const float tok_norm = sh_sc[q][0];
    if (tok_norm > 0.0f) {
        e0 = __fdiv_rn(__fmul_rn(e0, enorm), tok_norm);   // (emb*emb_norm)/tok_norm
        e1 = __fdiv_rn(__fmul_rn(e1, enorm), tok_norm);
    }
    sh_e[q][d0] = e0; sh_e[q][d1] = e1;
    sh_x[q][d0] = __fmul_rn(e0, e0);
    sh_x[q][d1] = __fmul_rn(e1, e1);
    __syncthreads();                                         // B3

    // e_in = ||normalized emb|| (reference recomputes it); valid at htid 0
    ps = np_pairwise512(sh_x[q], htid);
    const float e_in = __fsqrt_rn(ps);

    // ======== per-token wave-0 stretch: proj GEMV + Golay (registers) ======
    if (w4 == 0) {
        // proj = emb @ W_enc + b_enc (sequential-k FMA from LDS), lane l<24
        float p = 0.0f;
        if (hlane < 24) {
            float acc = 0.0f;
            #pragma unroll 8
            for (int d = 0; d < DD; d++)
                acc = fmaf(sh_e[q][d], sh_w[d * 24 + hlane], acc);
            p = __fadd_rn(acc, b_enc[hlane]);
        }

        // Golay encode + quantize (lanes 0..11), increasing-l order
        float latt = 0.0f;
        {
            const int k = hlane;
            float g = p;                         // l<12 terms: only l==k nonzero
            #pragma unroll
            for (int l = 12; l < 23; l++) {
                const float v = __shfl(p, l, 64);
                if ((k + l) & 1) g = __fadd_rn(g, v);
            }
            const float v23 = __shfl(p, 23, 64);
            if (k & 1) g = __fadd_rn(g, v23);
            latt = __fmul_rn(rintf(__fdiv_rn(g, ecc)), ecc);  // np.round = rint
        }

        // energy rescale (identical __f*_rn ops / order as r4-r9)
        float lt[12];
        #pragma unroll
        for (int k = 0; k < 12; k++) lt[k] = __shfl(latt, k, 64);
        float m1;
        {
            float sq[12];
            #pragma unroll
            for (int k = 0; k < 12; k++) sq[k] = __fmul_rn(lt[k], lt[k]);
            const float e_out = __fsqrt_rn(np_pairwise12(sq));
            m1 = __fdiv_rn(e_in, __fadd_rn(e_out, 1e-8f));    // e_in valid lane 0
        }
        m1 = __shfl(m1, 0, 64);                               // broadcast lane 0's m1
        float lv[12];
        #pragma unroll
        for (int k = 0; k < 12; k++) lv[k] = __fmul_rn(__fmul_rn(lt[k], m1), ep);
        if (hlane == 0) {
            float sq[12];
            #pragma unroll
            for (int k = 0; k < 12; k++) sq[k] = __fmul_rn(lv[k], lv[k]);
            sh_sc[q][2] = __fsqrt_rn(np_pairwise12(sq));   // e_in2 = ||scaled latt||
        }

        // Golay decode + ECC threshold (lanes 0..23), increasing-k order
        if (hlane < 24) {
            const int l = hlane;
            float g;
            if (l < 12) {
                g = lv[l];
            } else if (l < 23) {
                g = 0.0f;
                #pragma unroll
                for (int k = 0; k < 12; k++)
                    if ((k + l) & 1) g = __fadd_rn(g, lv[k]);
            } else {
                g = 0.0f;
                for (int k = 1; k < 12; k += 2) g = __fadd_rn(g, lv[k]);
            }
            sh_c[q][l] = (fabsf(g) > ecc) ? g : 0.0f;
        }
    }
    __syncthreads();                                         // B4

    // ---- res = corrected @ W_dec + b_dec (sequential-k FMA), then rescale ----
    float r0 = 0.0f, r1 = 0.0f;
    #pragma unroll
    for (int l = 0; l < 24; l++) {
        const float cl = sh_c[q][l];
        r0 = fmaf(cl, W_dec[l * DD + d0], r0);
        r1 = fmaf(cl, W_dec[l * DD + d1], r1);
    }
    r0 = __fadd_rn(r0, b_dec[d0]);
    r1 = __fadd_rn(r1, b_dec[d1]);
    sh_x[q][d0] = __fmul_rn(r0, r0);
    sh_x[q][d1] = __fmul_rn(r1, r1);
    __syncthreads();                                         // B5
    ps = np_pairwise512(sh_x[q], htid);
    if (htid == 0) sh_sc[q][3] = __fsqrt_rn(ps);    // e_out2
    __syncthreads();                                         // B6

    const float m2 = __fdiv_rn(sh_sc[q][2], __fadd_rn(sh_sc[q][3], 1e-8f));
    const float f0 = __fmul_rn(__fmul_rn(r0, m2), ep);   // unscaled res, kept in regs
    const float f1 = __fmul_rn(__fmul_rn(r1, m2), ep);

    // ---- per-token sum of squares for ||res||_F (smooth: f64) ----
    double v4 = (double)f0 * (double)f0 + (double)f1 * (double)f1;
    for (int off = 32; off > 0; off >>= 1) v4 += __shfl_down(v4, off, 64);
    if (hlane == 0) sh_red[q][w4] = v4;
    __syncthreads();                                         // B7
    if (htid == 0)
        partials[tok] = sh_red[q][0] + sh_red[q][1] + sh_red[q][2] + sh_red[q][3];
    __syncthreads();                                         // B8 (drain stores)

    // ---- grid barrier: agent-scope release arrival + relaxed spin +
    //      acquire exit (G16). Grid is co-resident (256 blocks, <=2/CU res). --
    if (tid == 0) {
        __hip_atomic_fetch_add(counter, 1u, __ATOMIC_RELEASE, __HIP_MEMORY_SCOPE_AGENT);
        const unsigned tgt_a = 0xAAAAAAAAu + 256u;  // d_ws poisoned to 0xAA
        const unsigned tgt_0 = 256u;                // zero-init fallback
        int it = 0;
        for (;;) {
            const unsigned c = __hip_atomic_load(counter, __ATOMIC_RELAXED,
                                                 __HIP_MEMORY_SCOPE_AGENT);
            if (c == tgt_a || c == tgt_0 || ++it > 200000) break;  // cap ~5ms
            __builtin_amdgcn_s_sleep(2);
        }
        (void)__hip_atomic_load(counter, __ATOMIC_ACQUIRE, __HIP_MEMORY_SCOPE_AGENT);
    }
    __syncthreads();                                         // B9

    // ---- factor = frac_norm * sqrt(sum of 1024 partials), redundant/block
    // (fd cancels: _fractal_dimension returns fd*frac_norm*||res||/|fd| with
    //  fd = clip(..,1,2.5) >= 1 > 0, so factor = frac_norm*||res||_F up to
    //  1 ulp; smooth scalar — reduction order-insensitive at ~1e-13 rel;
    //  scale_weights / fractal_bias are provably dead inputs.) ----
    if (tid < 256) {
        double s = 0.0;
        #pragma unroll
        for (int i = 0; i < 4; i++) s += partials[tid + 256 * i];
        for (int off = 32; off > 0; off >>= 1) s += __shfl_down(s, off, 64);
        if ((tid & 63) == 0) sh_fr[tid >> 6] = s;
    }
    __syncthreads();                                         // B10
    if (tid == 0)
        sh_factor = (float)((double)frac_norm[0] *
                            sqrt(sh_fr[0] + sh_fr[1] + sh_fr[2] + sh_fr[3]));
    __syncthreads();                                         // B11

    const float factor = sh_factor;
    out[tok * DD + d0] = __fmul_rn(f0, factor);
    out[tok * DD + d1] = __fmul_rn(f1, factor);
}

extern "C" void kernel_launch(void* const* d_in, const int* in_sizes, int n_in,
                              void* d_out, int out_size, void* d_ws, size_t ws_size,
                              hipStream_t stream)
{
    const int*   token_ids  = (const int*)  d_in[0];
    const float* resonances = (const float*)d_in[1];
    const float* emb_scales = (const float*)d_in[2];
    const float* emb_shifts = (const float*)d_in[3];
    const float* emb_norm   = (const float*)d_in[4];
    // d_in[5] scale_weights, d_in[6] fractal_bias: dead (fd cancellation)
    const float* frac_norm  = (const float*)d_in[7];
    const float* W_enc      = (const float*)d_in[8];
    const float* b_enc      = (const float*)d_in[9];
    const float* W_dec      = (const float*)d_in[10];
    const float* b_dec      = (const float*)d_in[11];
    const float* ecc        = (const float*)d_in[12];
    const float* ep         = (const float*)d_in[13];

    double*   partials = (double*)d_ws;                       // 1024 f64, all written
    unsigned* counter  = (unsigned*)((char*)d_ws + NT * sizeof(double));

    token_kernel<<<NT / 4, 1024, 0, stream>>>(token_ids, resonances, emb_scales,
                                              emb_shifts, emb_norm, W_enc, b_enc,
                                              W_dec, b_dec, ecc, ep, frac_norm,
                                              (float*)d_out, partials, counter);
}

// Round 11
// 95.752 us; speedup vs baseline: 1.0677x; 1.0677x over previous
//
#include <hip/hip_runtime.h>
#include <math.h>

// Problem constants (B=2, T=512, D=512)
#define NT   1024   // B*T tokens
#define TT   512    // T
#define DD   512    // D

// Extended Golay (24,12) generator, hardcoded (matches reference _golay()):
//   l <  12 : G[k][l] = (k==l)
//   l 12-22 : G[k][l] = (k+l)&1
//   l == 23 : G[k][l] = k&1
//
// PASSING STRATEGY (round 4, absmax 1.56e-2, stable r4-r10): faithful f32
// emulation of the f32 numpy reference — exact IEEE f32 ops (__f*_rn, no FMA
// contraction), correctly-rounded f32 sin/cos via f64 sincos, np.round =
// rintf, numpy's pairwise-summation order for norms, sequential-k fmaf GEMVs.
// DO NOT change any summation order that feeds round()/threshold decisions.
//
// ROUND 11 (perf; per-token arithmetic bit-identical to r9):
//  - REVERT r10's in-kernel grid barrier (REGRESSED +7us: spin-poll
//    contention across XCDs + per-block post-barrier partials re-read beat
//    by a plain second dispatch). Two-kernel structure restored.
//  - NEW: stage W_dec into LDS alongside W_enc (96 KB staged, ~112 KB LDS
//    total; grid=256=CU count -> 1 block/CU regardless, and r7/r9 showed
//    same-ladder occupancy doesn't matter). Removes the 48 KB L2-latency
//    bubble from the post-B4 W_dec GEMV critical path; LDS reads are
//    2 lanes/bank = conflict-free.

// numpy pairwise sum of 512 floats, exact numpy order (see r4). Runs on
// lanes 0..31 of the calling token's wave 0 (htid = thread-in-token).
// Result valid at htid == 0.
__device__ __forceinline__ float np_pairwise512(const float* x, int htid) {
    float r = 0.0f;
    if (htid < 32) {
        const int b = htid >> 3, j = htid & 7;
        const float* p = x + 128 * b + j;
        r = p[0];
        #pragma unroll
        for (int i = 1; i < 16; i++) r = __fadd_rn(r, p[8 * i]);
    }
    r = __fadd_rn(r, __shfl_down(r, 1, 64));
    r = __fadd_rn(r, __shfl_down(r, 2, 64));
    r = __fadd_rn(r, __shfl_down(r, 4, 64));
    r = __fadd_rn(r, __shfl_down(r, 8, 64));
    r = __fadd_rn(r, __shfl_down(r, 16, 64));
    return r;
}

// numpy pairwise sum, n=12 (8<=n<=128 path): combine first 8, then
// sequential remainder a[8..11].
__device__ __forceinline__ float np_pairwise12(const float* a) {
    float r = __fadd_rn(__fadd_rn(__fadd_rn(a[0], a[1]), __fadd_rn(a[2], a[3])),
                        __fadd_rn(__fadd_rn(a[4], a[5]), __fadd_rn(a[6], a[7])));
    r = __fadd_rn(r, a[8]);
    r = __fadd_rn(r, a[9]);
    r = __fadd_rn(r, a[10]);
    r = __fadd_rn(r, a[11]);
    return r;
}

__global__ __launch_bounds__(1024) void token_kernel(
    const int*   __restrict__ token_ids,
    const float* __restrict__ resonances,
    const float* __restrict__ emb_scales,
    const float* __restrict__ emb_shifts,
    const float* __restrict__ emb_norm,
    const float* __restrict__ W_enc,   // [D,24] row-major
    const float* __restrict__ b_enc,   // [24]
    const float* __restrict__ W_dec,   // [24,D] row-major
    const float* __restrict__ b_dec,   // [D]
    const float* __restrict__ ecc_p,   // [1]
    const float* __restrict__ ep_p,    // [1]
    float*       __restrict__ out,     // [NT*D] f32 (scaled in place later)
    double*      __restrict__ partials)// [NT] per-token sum of squares
{
    const int tid  = threadIdx.x;
    const int q    = tid >> 8;        // token slot 0..3 (waves 4q..4q+3)
    const int htid = tid & 255;       // thread-in-token
    const int tok  = blockIdx.x * 4 + q;
    const int t    = tok % TT;
    const int w4   = htid >> 6;       // wave-in-token 0..3
    const int hlane = htid & 63;      // lane within wave (256-aligned split)

    __shared__ float  sh_w[DD * 24];   // staged W_enc (48 KB, shared by 4 tokens)
    __shared__ float  sh_wd[24 * DD];  // staged W_dec (48 KB, shared by 4 tokens)
    __shared__ float  sh_e[4][DD];     // normalized emb
    __shared__ float  sh_x[4][DD];     // squares scratch
    __shared__ float  sh_c[4][24];     // corrected (decode output)
    __shared__ float  sh_sc[4][4];     // [q][0]: tok_norm, [2]: e_in2, [3]: e_out2
    __shared__ double sh_red[4][4];

    // ---- stage W_enc + W_dec -> LDS (coalesced float4; hides under sincos;
    //      W_enc first consumed after B3, W_dec after B4) ----
    {
        const float4* se = (const float4*)W_enc;
        float4*       de = (float4*)sh_w;
        const float4* sd = (const float4*)W_dec;
        float4*       dd = (float4*)sh_wd;
        #pragma unroll
        for (int i = 0; i < 3; i++) {         // 3 * 1024 = 3072 float4 = 48 KB each
            de[tid + 1024 * i] = se[tid + 1024 * i];
            dd[tid + 1024 * i] = sd[tid + 1024 * i];
        }
    }

    const float ecc   = ecc_p[0];
    const float ep    = ep_p[0];
    const float enorm = emb_norm[0];

    const int   idv  = token_ids[tok];                       // in [0,1e6): % identity
    const float tv   = __fdiv_rn((float)idv, 1000000.0f);    // exact np f32 div
    const float base = __fadd_rn(tv, (float)t);

    // ---- embedding (f32-exact): d0 = htid, d1 = htid+256 ----
    const int d0 = htid, d1 = htid + 256;
    float e0, e1;
    {
        const float a0 = __fmul_rn(resonances[d0], base);
        const float a1 = __fmul_rn(resonances[d1], base);
        // correctly-rounded f32 sin/cos via f64 sincos
        double s0d, c0d, s1d, c1d;
        sincos((double)a0, &s0d, &c0d);
        sincos((double)a1, &s1d, &c1d);
        const float s0 = (float)s0d, c0 = (float)c0d;
        const float s1 = (float)s1d, c1 = (float)c1d;
        const float comp0 = __fadd_rn(__fmul_rn(c0, __fadd_rn(1.0f, s0)), __fmul_rn(s0, s0));
        const float comp1 = __fadd_rn(__fmul_rn(c1, __fadd_rn(1.0f, s1)), __fmul_rn(s1, s1));
        e0 = __fadd_rn(__fmul_rn(comp0, emb_scales[d0]), emb_shifts[d0]);
        e1 = __fadd_rn(__fmul_rn(comp1, emb_scales[d1]), emb_shifts[d1]);
    }
    sh_x[q][d0] = __fmul_rn(e0, e0);
    sh_x[q][d1] = __fmul_rn(e1, e1);
    __syncthreads();                                         // B1

    // tok_norm (numpy pairwise + correctly-rounded sqrt)
    float ps = np_pairwise512(sh_x[q], htid);
    if (htid == 0) sh_sc[q][0] = __fsqrt_rn(ps);
    __syncthreads();                                         // B2
    const float tok_norm = sh_sc[q][0];
    if (tok_norm > 0.0f) {
        e0 = __fdiv_rn(__fmul_rn(e0, enorm), tok_norm);   // (emb*emb_norm)/tok_norm
        e1 = __fdiv_rn(__fmul_rn(e1, enorm), tok_norm);
    }
    sh_e[q][d0] = e0; sh_e[q][d1] = e1;
    sh_x[q][d0] = __fmul_rn(e0, e0);
    sh_x[q][d1] = __fmul_rn(e1, e1);
    __syncthreads();                                         // B3

    // e_in = ||normalized emb|| (reference recomputes it); valid at htid 0
    ps = np_pairwise512(sh_x[q], htid);
    const float e_in = __fsqrt_rn(ps);

    // ======== per-token wave-0 stretch: proj GEMV + Golay (registers) ======
    if (w4 == 0) {
        // proj = emb @ W_enc + b_enc (sequential-k FMA from LDS), lane l<24
        float p = 0.0f;
        if (hlane < 24) {
            float acc = 0.0f;
            #pragma unroll 8
            for (int d = 0; d < DD; d++)
                acc = fmaf(sh_e[q][d], sh_w[d * 24 + hlane], acc);
            p = __fadd_rn(acc, b_enc[hlane]);
        }

        // Golay encode + quantize (lanes 0..11), increasing-l order
        float latt = 0.0f;
        {
            const int k = hlane;
            float g = p;                         // l<12 terms: only l==k nonzero
            #pragma unroll
            for (int l = 12; l < 23; l++) {
                const float v = __shfl(p, l, 64);
                if ((k + l) & 1) g = __fadd_rn(g, v);
            }
            const float v23 = __shfl(p, 23, 64);
            if (k & 1) g = __fadd_rn(g, v23);
            latt = __fmul_rn(rintf(__fdiv_rn(g, ecc)), ecc);  // np.round = rint
        }

        // energy rescale (identical __f*_rn ops / order as r4-r10)
        float lt[12];
        #pragma unroll
        for (int k = 0; k < 12; k++) lt[k] = __shfl(latt, k, 64);
        float m1;
        {
            float sq[12];
            #pragma unroll
            for (int k = 0; k < 12; k++) sq[k] = __fmul_rn(lt[k], lt[k]);
            const float e_out = __fsqrt_rn(np_pairwise12(sq));
            m1 = __fdiv_rn(e_in, __fadd_rn(e_out, 1e-8f));    // e_in valid lane 0
        }
        m1 = __shfl(m1, 0, 64);                               // broadcast lane 0's m1
        float lv[12];
        #pragma unroll
        for (int k = 0; k < 12; k++) lv[k] = __fmul_rn(__fmul_rn(lt[k], m1), ep);
        if (hlane == 0) {
            float sq[12];
            #pragma unroll
            for (int k = 0; k < 12; k++) sq[k] = __fmul_rn(lv[k], lv[k]);
            sh_sc[q][2] = __fsqrt_rn(np_pairwise12(sq));   // e_in2 = ||scaled latt||
        }

        // Golay decode + ECC threshold (lanes 0..23), increasing-k order
        if (hlane < 24) {
            const int l = hlane;
            float g;
            if (l < 12) {
                g = lv[l];
            } else if (l < 23) {
                g = 0.0f;
                #pragma unroll
                for (int k = 0; k < 12; k++)
                    if ((k + l) & 1) g = __fadd_rn(g, lv[k]);
            } else {
                g = 0.0f;
                for (int k = 1; k < 12; k += 2) g = __fadd_rn(g, lv[k]);
            }
            sh_c[q][l] = (fabsf(g) > ecc) ? g : 0.0f;
        }
    }
    __syncthreads();                                         // B4

    // ---- res = corrected @ W_dec + b_dec (sequential-k FMA from LDS) ----
    float r0 = 0.0f, r1 = 0.0f;
    #pragma unroll
    for (int l = 0; l < 24; l++) {
        const float cl = sh_c[q][l];
        r0 = fmaf(cl, sh_wd[l * DD + d0], r0);
        r1 = fmaf(cl, sh_wd[l * DD + d1], r1);
    }
    r0 = __fadd_rn(r0, b_dec[d0]);
    r1 = __fadd_rn(r1, b_dec[d1]);
    sh_x[q][d0] = __fmul_rn(r0, r0);
    sh_x[q][d1] = __fmul_rn(r1, r1);
    __syncthreads();                                         // B5
    ps = np_pairwise512(sh_x[q], htid);
    if (htid == 0) sh_sc[q][3] = __fsqrt_rn(ps);    // e_out2
    __syncthreads();                                         // B6

    const float m2 = __fdiv_rn(sh_sc[q][2], __fadd_rn(sh_sc[q][3], 1e-8f));
    const float f0 = __fmul_rn(__fmul_rn(r0, m2), ep);
    const float f1 = __fmul_rn(__fmul_rn(r1, m2), ep);
    out[tok * DD + d0] = f0;
    out[tok * DD + d1] = f1;

    // ---- per-token sum of squares for ||res||_F (smooth: f64, no atomic) ----
    double v4 = (double)f0 * (double)f0 + (double)f1 * (double)f1;
    for (int off = 32; off > 0; off >>= 1) v4 += __shfl_down(v4, off, 64);
    if (hlane == 0) sh_red[q][w4] = v4;
    __syncthreads();                                         // B7
    if (htid == 0)
        partials[tok] = sh_red[q][0] + sh_red[q][1] + sh_red[q][2] + sh_red[q][3];
}

// In-place: out *= frac_norm * ||res||_F, factor redundantly reduced per
// block from the 1024 f64 partials (deterministic -> identical in every
// block; smooth scalar, order-insensitive).
// (fd cancels: _fractal_dimension returns fd*frac_norm*||res||/|fd| with
//  fd = clip(..,1,2.5) >= 1 > 0, so the factor is frac_norm*||res||_F up to
//  1 ulp; scale_weights / fractal_bias are provably dead inputs.)
__global__ __launch_bounds__(256) void scale_kernel(
    float*        __restrict__ out,
    const double* __restrict__ partials,
    const float*  __restrict__ frac_norm)
{
    const int tid = threadIdx.x;
    __shared__ double sh[4];
    __shared__ float sh_factor;
    double s = 0.0;
    #pragma unroll
    for (int i = 0; i < 4; i++) s += partials[tid + 256 * i];
    for (int off = 32; off > 0; off >>= 1) s += __shfl_down(s, off, 64);
    if ((tid & 63) == 0) sh[tid >> 6] = s;
    __syncthreads();
    if (tid == 0)
        sh_factor = (float)((double)frac_norm[0] * sqrt(sh[0] + sh[1] + sh[2] + sh[3]));
    __syncthreads();
    const float factor = sh_factor;

    const int i = blockIdx.x * blockDim.x + tid;   // one float4 per thread
    float4 r = ((const float4*)out)[i];
    r.x = __fmul_rn(r.x, factor);
    r.y = __fmul_rn(r.y, factor);
    r.z = __fmul_rn(r.z, factor);
    r.w = __fmul_rn(r.w, factor);
    ((float4*)out)[i] = r;
}

extern "C" void kernel_launch(void* const* d_in, const int* in_sizes, int n_in,
                              void* d_out, int out_size, void* d_ws, size_t ws_size,
                              hipStream_t stream)
{
    const int*   token_ids  = (const int*)  d_in[0];
    const float* resonances = (const float*)d_in[1];
    const float* emb_scales = (const float*)d_in[2];
    const float* emb_shifts = (const float*)d_in[3];
    const float* emb_norm   = (const float*)d_in[4];
    // d_in[5] scale_weights, d_in[6] fractal_bias: dead (fd cancellation)
    const float* frac_norm  = (const float*)d_in[7];
    const float* W_enc      = (const float*)d_in[8];
    const float* b_enc      = (const float*)d_in[9];
    const float* W_dec      = (const float*)d_in[10];
    const float* b_dec      = (const float*)d_in[11];
    const float* ecc        = (const float*)d_in[12];
    const float* ep         = (const float*)d_in[13];

    double* partials = (double*)d_ws;                       // 1024 doubles, all written

    token_kernel<<<NT / 4, 1024, 0, stream>>>(token_ids, resonances, emb_scales,
                                              emb_shifts, emb_norm, W_enc, b_enc,
                                              W_dec, b_dec, ecc, ep,
                                              (float*)d_out, partials);
    scale_kernel<<<(NT * DD) / 1024, 256, 0, stream>>>((float*)d_out, partials, frac_norm);
}

// Round 12
// 95.507 us; speedup vs baseline: 1.0704x; 1.0026x over previous
//
#include <hip/hip_runtime.h>
#include <math.h>

// Problem constants (B=2, T=512, D=512)
#define NT   1024   // B*T tokens
#define TT   512    // T
#define DD   512    // D

// Extended Golay (24,12) generator, hardcoded (matches reference _golay()):
//   l <  12 : G[k][l] = (k==l)
//   l 12-22 : G[k][l] = (k+l)&1
//   l == 23 : G[k][l] = k&1
//
// PASSING STRATEGY (round 4, absmax 1.56e-2, stable r4-r11): faithful f32
// emulation of the f32 numpy reference — exact IEEE f32 ops (__f*_rn, no FMA
// contraction), correctly-rounded f32 sin/cos via f64 sincos, np.round =
// rintf, numpy's pairwise-summation order for norms, sequential-k fmaf GEMVs.
// DO NOT change any summation order that feeds round()/threshold decisions.
//
// ROUND 12 (perf; decision arithmetic bit-identical to r9):
//  - Revert r11's W_dec LDS staging (neutral/slightly negative: the 24
//    independent L2 loads were never on the critical path).
//  - Barrier-ladder shortening: tok_norm (was B2) and e_out2 (was B6)
//    reductions are now REDUNDANT PER WAVE — each wave runs the identical
//    np_pairwise512 (lanes 0..31 pattern via hlane, same op order -> same
//    bits), broadcasts the sum in-wave (__shfl), applies __fsqrt_rn per
//    lane. sh_x2 double-buffer removes the RAW hazard B2 guarded.
//    7 block barriers -> 5, two LDS-scalar write->barrier->read hops gone.

// numpy pairwise sum of 512 floats, exact numpy order (see r4):
// 512 -> 2x256 -> 4x128; each 128-block: 8 accumulators r[j] (sequential
// over 16), combined ((r0+r1)+(r2+r3))+((r4+r5)+(r6+r7)); shfl_down(1,2,4)
// reproduces the combine, shfl_down(8,16) the block splits. Executed by
// lanes 0..31 of the CALLING WAVE (pass hlane); result valid at lane 0.
__device__ __forceinline__ float np_pairwise512(const float* x, int hlane) {
    float r = 0.0f;
    if (hlane < 32) {
        const int b = hlane >> 3, j = hlane & 7;
        const float* p = x + 128 * b + j;
        r = p[0];
        #pragma unroll
        for (int i = 1; i < 16; i++) r = __fadd_rn(r, p[8 * i]);
    }
    r = __fadd_rn(r, __shfl_down(r, 1, 64));
    r = __fadd_rn(r, __shfl_down(r, 2, 64));
    r = __fadd_rn(r, __shfl_down(r, 4, 64));
    r = __fadd_rn(r, __shfl_down(r, 8, 64));
    r = __fadd_rn(r, __shfl_down(r, 16, 64));
    return r;
}

// numpy pairwise sum, n=12 (8<=n<=128 path): combine first 8, then
// sequential remainder a[8..11].
__device__ __forceinline__ float np_pairwise12(const float* a) {
    float r = __fadd_rn(__fadd_rn(__fadd_rn(a[0], a[1]), __fadd_rn(a[2], a[3])),
                        __fadd_rn(__fadd_rn(a[4], a[5]), __fadd_rn(a[6], a[7])));
    r = __fadd_rn(r, a[8]);
    r = __fadd_rn(r, a[9]);
    r = __fadd_rn(r, a[10]);
    r = __fadd_rn(r, a[11]);
    return r;
}

__global__ __launch_bounds__(1024) void token_kernel(
    const int*   __restrict__ token_ids,
    const float* __restrict__ resonances,
    const float* __restrict__ emb_scales,
    const float* __restrict__ emb_shifts,
    const float* __restrict__ emb_norm,
    const float* __restrict__ W_enc,   // [D,24] row-major
    const float* __restrict__ b_enc,   // [24]
    const float* __restrict__ W_dec,   // [24,D] row-major
    const float* __restrict__ b_dec,   // [D]
    const float* __restrict__ ecc_p,   // [1]
    const float* __restrict__ ep_p,    // [1]
    float*       __restrict__ out,     // [NT*D] f32 (scaled in place later)
    double*      __restrict__ partials)// [NT] per-token sum of squares
{
    const int tid  = threadIdx.x;
    const int q    = tid >> 8;        // token slot 0..3 (waves 4q..4q+3)
    const int htid = tid & 255;       // thread-in-token
    const int tok  = blockIdx.x * 4 + q;
    const int t    = tok % TT;
    const int w4   = htid >> 6;       // wave-in-token 0..3
    const int hlane = htid & 63;      // lane within wave (256-aligned split)

    __shared__ float  sh_w[DD * 24];   // staged W_enc (48 KB, shared by 4 tokens)
    __shared__ float  sh_e[4][DD];     // normalized emb
    __shared__ float  sh_x[4][DD];     // emb^2, later res^2
    __shared__ float  sh_x2[4][DD];    // normalized emb^2 (double buffer, kills B2)
    __shared__ float  sh_c[4][24];     // corrected (decode output)
    __shared__ float  sh_sc[4][4];     // [q][2]: e_in2
    __shared__ double sh_red[4][4];

    // ---- stage W_enc -> LDS (coalesced float4; hides under sincos; first
    //      consumer is after B3) ----
    {
        const float4* src = (const float4*)W_enc;
        float4*       dst = (float4*)sh_w;
        #pragma unroll
        for (int i = 0; i < 3; i++)           // 3 * 1024 = 3072 float4 = 48 KB
            dst[tid + 1024 * i] = src[tid + 1024 * i];
    }

    const float ecc   = ecc_p[0];
    const float ep    = ep_p[0];
    const float enorm = emb_norm[0];

    const int   idv  = token_ids[tok];                       // in [0,1e6): % identity
    const float tv   = __fdiv_rn((float)idv, 1000000.0f);    // exact np f32 div
    const float base = __fadd_rn(tv, (float)t);

    // ---- embedding (f32-exact): d0 = htid, d1 = htid+256 ----
    const int d0 = htid, d1 = htid + 256;
    float e0, e1;
    {
        const float a0 = __fmul_rn(resonances[d0], base);
        const float a1 = __fmul_rn(resonances[d1], base);
        // correctly-rounded f32 sin/cos via f64 sincos
        double s0d, c0d, s1d, c1d;
        sincos((double)a0, &s0d, &c0d);
        sincos((double)a1, &s1d, &c1d);
        const float s0 = (float)s0d, c0 = (float)c0d;
        const float s1 = (float)s1d, c1 = (float)c1d;
        const float comp0 = __fadd_rn(__fmul_rn(c0, __fadd_rn(1.0f, s0)), __fmul_rn(s0, s0));
        const float comp1 = __fadd_rn(__fmul_rn(c1, __fadd_rn(1.0f, s1)), __fmul_rn(s1, s1));
        e0 = __fadd_rn(__fmul_rn(comp0, emb_scales[d0]), emb_shifts[d0]);
        e1 = __fadd_rn(__fmul_rn(comp1, emb_scales[d1]), emb_shifts[d1]);
    }
    sh_x[q][d0] = __fmul_rn(e0, e0);
    sh_x[q][d1] = __fmul_rn(e1, e1);
    __syncthreads();                                         // B1

    // tok_norm: redundant per-wave reduction (identical bits in every wave;
    // broadcast the SUM then sqrt per lane — same rounding as reference)
    float ps = np_pairwise512(sh_x[q], hlane);
    const float tok_norm = __fsqrt_rn(__shfl(ps, 0, 64));
    if (tok_norm > 0.0f) {
        e0 = __fdiv_rn(__fmul_rn(e0, enorm), tok_norm);   // (emb*emb_norm)/tok_norm
        e1 = __fdiv_rn(__fmul_rn(e1, enorm), tok_norm);
    }
    sh_e[q][d0] = e0; sh_e[q][d1] = e1;
    sh_x2[q][d0] = __fmul_rn(e0, e0);     // double buffer: sh_x still being read
    sh_x2[q][d1] = __fmul_rn(e1, e1);
    __syncthreads();                                         // B3

    // ======== per-token wave-0 stretch: e_in + proj GEMV + Golay ==========
    if (w4 == 0) {
        // e_in = ||normalized emb|| (reference recomputes it); valid lane 0
        ps = np_pairwise512(sh_x2[q], hlane);
        const float e_in = __fsqrt_rn(ps);

        // proj = emb @ W_enc + b_enc (sequential-k FMA from LDS), lane l<24
        float p = 0.0f;
        if (hlane < 24) {
            float acc = 0.0f;
            #pragma unroll 8
            for (int d = 0; d < DD; d++)
                acc = fmaf(sh_e[q][d], sh_w[d * 24 + hlane], acc);
            p = __fadd_rn(acc, b_enc[hlane]);
        }

        // Golay encode + quantize (lanes 0..11), increasing-l order
        float latt = 0.0f;
        {
            const int k = hlane;
            float g = p;                         // l<12 terms: only l==k nonzero
            #pragma unroll
            for (int l = 12; l < 23; l++) {
                const float v = __shfl(p, l, 64);
                if ((k + l) & 1) g = __fadd_rn(g, v);
            }
            const float v23 = __shfl(p, 23, 64);
            if (k & 1) g = __fadd_rn(g, v23);
            latt = __fmul_rn(rintf(__fdiv_rn(g, ecc)), ecc);  // np.round = rint
        }

        // energy rescale (identical __f*_rn ops / order as r4-r11)
        float lt[12];
        #pragma unroll
        for (int k = 0; k < 12; k++) lt[k] = __shfl(latt, k, 64);
        float m1;
        {
            float sq[12];
            #pragma unroll
            for (int k = 0; k < 12; k++) sq[k] = __fmul_rn(lt[k], lt[k]);
            const float e_out = __fsqrt_rn(np_pairwise12(sq));
            m1 = __fdiv_rn(e_in, __fadd_rn(e_out, 1e-8f));    // e_in valid lane 0
        }
        m1 = __shfl(m1, 0, 64);                               // broadcast lane 0's m1
        float lv[12];
        #pragma unroll
        for (int k = 0; k < 12; k++) lv[k] = __fmul_rn(__fmul_rn(lt[k], m1), ep);
        if (hlane == 0) {
            float sq[12];
            #pragma unroll
            for (int k = 0; k < 12; k++) sq[k] = __fmul_rn(lv[k], lv[k]);
            sh_sc[q][2] = __fsqrt_rn(np_pairwise12(sq));   // e_in2 = ||scaled latt||
        }

        // Golay decode + ECC threshold (lanes 0..23), increasing-k order
        if (hlane < 24) {
            const int l = hlane;
            float g;
            if (l < 12) {
                g = lv[l];
            } else if (l < 23) {
                g = 0.0f;
                #pragma unroll
                for (int k = 0; k < 12; k++)
                    if ((k + l) & 1) g = __fadd_rn(g, lv[k]);
            } else {
                g = 0.0f;
                for (int k = 1; k < 12; k += 2) g = __fadd_rn(g, lv[k]);
            }
            sh_c[q][l] = (fabsf(g) > ecc) ? g : 0.0f;
        }
    }
    __syncthreads();                                         // B4

    // ---- res = corrected @ W_dec + b_dec (sequential-k FMA, L2-resident) ----
    float r0 = 0.0f, r1 = 0.0f;
    #pragma unroll
    for (int l = 0; l < 24; l++) {
        const float cl = sh_c[q][l];
        r0 = fmaf(cl, W_dec[l * DD + d0], r0);
        r1 = fmaf(cl, W_dec[l * DD + d1], r1);
    }
    r0 = __fadd_rn(r0, b_dec[d0]);
    r1 = __fadd_rn(r1, b_dec[d1]);
    sh_x[q][d0] = __fmul_rn(r0, r0);   // sh_x last read pre-B3: safe to reuse
    sh_x[q][d1] = __fmul_rn(r1, r1);
    __syncthreads();                                         // B5

    // e_out2: redundant per-wave reduction (identical bits), no barrier after
    ps = np_pairwise512(sh_x[q], hlane);
    const float e_out2 = __fsqrt_rn(__shfl(ps, 0, 64));
    const float m2 = __fdiv_rn(sh_sc[q][2], __fadd_rn(e_out2, 1e-8f)); // e_in2 visible since B4
    const float f0 = __fmul_rn(__fmul_rn(r0, m2), ep);
    const float f1 = __fmul_rn(__fmul_rn(r1, m2), ep);
    out[tok * DD + d0] = f0;
    out[tok * DD + d1] = f1;

    // ---- per-token sum of squares for ||res||_F (smooth: f64, no atomic) ----
    double v4 = (double)f0 * (double)f0 + (double)f1 * (double)f1;
    for (int off = 32; off > 0; off >>= 1) v4 += __shfl_down(v4, off, 64);
    if (hlane == 0) sh_red[q][w4] = v4;
    __syncthreads();                                         // B7
    if (htid == 0)
        partials[tok] = sh_red[q][0] + sh_red[q][1] + sh_red[q][2] + sh_red[q][3];
}

// In-place: out *= frac_norm * ||res||_F, factor redundantly reduced per
// block from the 1024 f64 partials (deterministic -> identical in every
// block; smooth scalar, order-insensitive).
// (fd cancels: _fractal_dimension returns fd*frac_norm*||res||/|fd| with
//  fd = clip(..,1,2.5) >= 1 > 0, so the factor is frac_norm*||res||_F up to
//  1 ulp; scale_weights / fractal_bias are provably dead inputs.)
__global__ __launch_bounds__(256) void scale_kernel(
    float*        __restrict__ out,
    const double* __restrict__ partials,
    const float*  __restrict__ frac_norm)
{
    const int tid = threadIdx.x;
    __shared__ double sh[4];
    __shared__ float sh_factor;
    double s = 0.0;
    #pragma unroll
    for (int i = 0; i < 4; i++) s += partials[tid + 256 * i];
    for (int off = 32; off > 0; off >>= 1) s += __shfl_down(s, off, 64);
    if ((tid & 63) == 0) sh[tid >> 6] = s;
    __syncthreads();
    if (tid == 0)
        sh_factor = (float)((double)frac_norm[0] * sqrt(sh[0] + sh[1] + sh[2] + sh[3]));
    __syncthreads();
    const float factor = sh_factor;

    const int i = blockIdx.x * blockDim.x + tid;   // one float4 per thread
    float4 r = ((const float4*)out)[i];
    r.x = __fmul_rn(r.x, factor);
    r.y = __fmul_rn(r.y, factor);
    r.z = __fmul_rn(r.z, factor);
    r.w = __fmul_rn(r.w, factor);
    ((float4*)out)[i] = r;
}

extern "C" void kernel_launch(void* const* d_in, const int* in_sizes, int n_in,
                              void* d_out, int out_size, void* d_ws, size_t ws_size,
                              hipStream_t stream)
{
    const int*   token_ids  = (const int*)  d_in[0];
    const float* resonances = (const float*)d_in[1];
    const float* emb_scales = (const float*)d_in[2];
    const float* emb_shifts = (const float*)d_in[3];
    const float* emb_norm   = (const float*)d_in[4];
    // d_in[5] scale_weights, d_in[6] fractal_bias: dead (fd cancellation)
    const float* frac_norm  = (const float*)d_in[7];
    const float* W_enc      = (const float*)d_in[8];
    const float* b_enc      = (const float*)d_in[9];
    const float* W_dec      = (const float*)d_in[10];
    const float* b_dec      = (const float*)d_in[11];
    const float* ecc        = (const float*)d_in[12];
    const float* ep         = (const float*)d_in[13];

    double* partials = (double*)d_ws;                       // 1024 doubles, all written

    token_kernel<<<NT / 4, 1024, 0, stream>>>(token_ids, resonances, emb_scales,
                                              emb_shifts, emb_norm, W_enc, b_enc,
                                              W_dec, b_dec, ecc, ep,
                                              (float*)d_out, partials);
    scale_kernel<<<(NT * DD) / 1024, 256, 0, stream>>>((float*)d_out, partials, frac_norm);
}